// Round 5
// baseline (290.702 us; speedup 1.0000x reference)
//
#include <hip/hip_runtime.h>
#include <math.h>

// Real grid (match reference): 421 x 421 E-grid, source at (210,210)
#define NXr 421
#define CXr 210
#define NSTEPS_C 200

// Round 16: cut REDUNDANCY at constant phase count / constant per-thread body.
// Champion (R12/R14): Bt=16, Kt=8, EXT=32 -> redundancy 4x, 256 thr/block.
// Now: Bt=32, Kt=8, EXT=48 -> redundancy (48/32)^2 = 2.25x (stepped cells
// x0.60), 24x24 threads x 2x2 cells = 576 thr = 9 waves/block. Late grid
// 14x14=196 blocks -> 1 block/CU x 9 waves (vs R15's fatal 4 waves/CU).
// Same verified 2x2 step body; same 23 dispatches (init + seed + 21 phases).
// R15 lesson: phase time is chain-latency x steps, hidden by waves/CU -> keep
// waves high while shrinking total work.
#define Bt   32
#define Kt   8
#define EXT  48                    // 24x24 threads x 2x2 cells
#define TDIM 24                    // threads per side
#define NTHR (TDIM * TDIM)         // 576 = 9 waves
#define LROWS (EXT + 2)            // 50: zero ring row above/below
#define SPITCH 52                  // 2+48+2 cols, even => float2-aligned interior
#define NBLK 14                    // 14*32 = 448 >= 421; owned tiles real [0,448)
#define OWN_T0 4                   // owned cells [8,40) -> ti,tj in [4,20)
#define OWN_T1 20

// Padded zero-ring layout: fields are PP x PP with the real 421^2 domain at
// offset (PAD,PAD), PAD = Kt. Coefficient tables are zero outside the real
// domain, so cells outside it provably stay 0 forever -> all hot loads/stores
// are unconditional float2. A zeroed guard row (PP floats) sits in front of
// the field block so ghost loads at padded row/col -1 are safe.
// Max tile extent: 13*32 + 48 = 464 = PP exactly.
#define PP   464
#define PAD  8
#define CP   (CXr + PAD)           // source in padded coords: 218
#define FSZ  (PP * PP)             // floats per padded field

// Seed tile: 64x64 cells at rows/cols [SB, SB+64) = [CP-32, CP+32)
#define SB   (CP - 32)             // 186
#define SROWS 66                   // 1 + 64 + 1 ring rows
#define SPITCH2 72                 // 4 + 64 + 4 cols, float4-aligned interior
#define SEED_STEPS 32              // support radius <= 31 stays inside tile

struct PParams {
    float *aEz, *aEo, *aJz, *aJo, *aHx, *aHy;   // state set A
    float *bEz, *bEo, *bJz, *bJo, *bHx, *bHy;   // state set B
    const float *dexP, *deyP, *aexP, *aeyP, *ahxP, *ahyP;  // padded 1-D tables
    const float *C1a, *C2a, *Cbdxa, *Cbdya;
    const float *Caa, *Cba, *Cca, *Cda, *Cea, *dbhxa, *dbhya;
    const float *src;
};

// ---------------------------------------------------------------------------
// Init: zero guard row + both padded state sets; build padded coeff tables.
// dexP/deyP fold the interior mask (nonzero only for real coords 1..419).
// Zeroing BOTH sets every call keeps the support-gating skip exact.
// ---------------------------------------------------------------------------
__global__ void init_kernel(const float* __restrict__ sig_ex,
                            const float* __restrict__ sig_ey,
                            const float* __restrict__ sig_hx,
                            const float* __restrict__ sig_hy,
                            float de_fac, float dh_fac,
                            float* __restrict__ zero_base, int n_zero,
                            float* __restrict__ dexP, float* __restrict__ deyP,
                            float* __restrict__ aexP, float* __restrict__ aeyP,
                            float* __restrict__ ahxP, float* __restrict__ ahyP)
{
    int t = blockIdx.x * blockDim.x + threadIdx.x;
    int stride = gridDim.x * blockDim.x;
    for (int k = t; k < n_zero; k += stride) zero_base[k] = 0.0f;
    if (t < PP) {
        int g = t - PAD;
        dexP[t] = (g >= 1 && g <= NXr - 2) ? expf(-sig_ex[g] * de_fac) : 0.0f;
        deyP[t] = (g >= 1 && g <= NXr - 2) ? expf(-sig_ey[g] * de_fac) : 0.0f;
        aexP[t] = (g >= 0 && g <  NXr)     ? expf(-sig_ex[g] * dh_fac) : 0.0f;
        aeyP[t] = (g >= 0 && g <  NXr)     ? expf(-sig_ey[g] * dh_fac) : 0.0f;
        ahxP[t] = (g >= 0 && g <  NXr - 1) ? expf(-sig_hx[g] * dh_fac) : 0.0f;
        ahyP[t] = (g >= 0 && g <  NXr - 1) ? expf(-sig_hy[g] * dh_fac) : 0.0f;
    }
}

// ---------------------------------------------------------------------------
// Seed: steps 0..31 in one dispatch, one block. 16x16 threads x 4x4 cells =
// 64x64 tile centered on the source. State starts at exact zero (no global
// loads). Ring reads return 0 = true field (support radius <= 31 stays
// strictly inside). Writes state-of-step-32 to set A. (Verified R14/R15.)
// ---------------------------------------------------------------------------
__global__ __launch_bounds__(256, 1)
void seed_kernel(PParams p)
{
    __shared__ __align__(16) float sE[2][SROWS][SPITCH2];

    const int tid = threadIdx.x;
    const int tj = tid & 15, ti = tid >> 4;
    const int li0 = 4 * ti, lj0 = 4 * tj;     // local cell origin (0..60)
    const int r0 = SB + li0, c0 = SB + lj0;   // padded coords

    const float ca = p.Caa[0], cb = p.Cba[0], cc = p.Cca[0];
    const float cd = p.Cda[0], ce = p.Cea[0];
    const float ca1 = ca + 1.0f;
    const float C1 = p.C1a[0], C2 = p.C2a[0];
    const float cbdx = p.Cbdxa[0], cbdy = p.Cbdya[0];
    const float dbhx0 = p.dbhxa[0], dbhy0 = p.dbhya[0];

    float dHx[4][4], dHy[4][4], dE[4][4], dHyU[4], dHxL[4], srcw[4][4];
#pragma unroll
    for (int a = 0; a < 4; ++a)
#pragma unroll
        for (int b = 0; b < 4; ++b) {
            dHx[a][b] = p.aexP[r0 + a] * p.ahyP[c0 + b];
            dHy[a][b] = p.ahxP[r0 + a] * p.aeyP[c0 + b];
            dE[a][b]  = p.dexP[r0 + a] * p.deyP[c0 + b];
            srcw[a][b] = ((r0 + a == CP) && (c0 + b == CP)) ? 1.0f : 0.0f;
        }
    {
        float ahxU = p.ahxP[r0 - 1];          // r0-1 >= SB-1 = 185 >= 0
        float ahyL = p.ahyP[c0 - 1];
#pragma unroll
        for (int b = 0; b < 4; ++b) dHyU[b] = ahxU * p.aeyP[c0 + b];
#pragma unroll
        for (int a = 0; a < 4; ++a) dHxL[a] = p.aexP[r0 + a] * ahyL;
    }

    // Zero state (exact at t=0) -- no global loads at all.
    float ez[4][4] = {}, eo[4][4] = {}, jz[4][4] = {}, jo[4][4] = {};
    float hx[4][4] = {}, hy[4][4] = {};
    float hyU[4] = {}, hxL[4] = {};

    {
        float* sp = &sE[0][0][0];
        for (int z = tid; z < 2 * SROWS * SPITCH2; z += 256) sp[z] = 0.0f;
    }
    __syncthreads();

#pragma unroll 2
    for (int s = 0; s < SEED_STEPS; ++s) {
        float sv = p.src[s];
        float (*S)[SPITCH2] = sE[s & 1];
#pragma unroll
        for (int a = 0; a < 4; ++a)
            *(float4*)&S[1 + li0 + a][4 + lj0] =
                make_float4(ez[a][0], ez[a][1], ez[a][2], ez[a][3]);

        // own-only H components (no neighbor deps) before the barrier
#pragma unroll
        for (int a = 0; a < 4; ++a)
#pragma unroll
            for (int b = 0; b < 3; ++b)
                hx[a][b] = dHx[a][b] * (hx[a][b] - dbhx0 * (ez[a][b+1] - ez[a][b]));
#pragma unroll
        for (int a = 0; a < 3; ++a)
#pragma unroll
            for (int b = 0; b < 4; ++b)
                hy[a][b] = dHy[a][b] * (hy[a][b] + dbhy0 * (ez[a+1][b] - ez[a][b]));

        __syncthreads();

        float eR[4], eL[4];
#pragma unroll
        for (int a = 0; a < 4; ++a) {
            eR[a] = S[1 + li0 + a][4 + lj0 + 4];
            eL[a] = S[1 + li0 + a][3 + lj0];
        }
        float4 eD = *(float4*)&S[1 + li0 + 4][4 + lj0];
        float4 eU = *(float4*)&S[li0][4 + lj0];
        float eDv[4] = {eD.x, eD.y, eD.z, eD.w};
        float eUv[4] = {eU.x, eU.y, eU.z, eU.w};

#pragma unroll
        for (int a = 0; a < 4; ++a)
            hx[a][3] = dHx[a][3] * (hx[a][3] - dbhx0 * (eR[a] - ez[a][3]));
#pragma unroll
        for (int b = 0; b < 4; ++b)
            hy[3][b] = dHy[3][b] * (hy[3][b] + dbhy0 * (eDv[b] - ez[3][b]));
#pragma unroll
        for (int b = 0; b < 4; ++b)
            hyU[b] = dHyU[b] * (hyU[b] + dbhy0 * (ez[0][b] - eUv[b]));
#pragma unroll
        for (int a = 0; a < 4; ++a)
            hxL[a] = dHxL[a] * (hxL[a] - dbhx0 * (ez[a][0] - eL[a]));

#pragma unroll
        for (int a = 0; a < 4; ++a)
#pragma unroll
            for (int b = 0; b < 4; ++b) {
                float cHyv = hy[a][b] - (a == 0 ? hyU[b] : hy[a-1][b]);
                float cHxv = hx[a][b] - (b == 0 ? hxL[a] : hx[a][b-1]);
                float e = ez[a][b], j = jz[a][b];
                float phi = ca1 * j + cb * jo[a][b] + cd * e + ce * eo[a][b];
                float v1 = fmaf(-C2, phi, C1 * e);
                float v2 = fmaf(cbdx, cHyv, v1);
                float en = dE[a][b] * fmaf(-cbdy, cHxv, v2);
                en = fmaf(srcw[a][b], sv, en);
                float jn = fmaf(cc, en, phi - j);
                eo[a][b] = e;  ez[a][b] = en;
                jo[a][b] = j;  jz[a][b] = jn;
            }
    }

#pragma unroll
    for (int a = 0; a < 4; ++a) {
        int g = (r0 + a) * PP + c0;
        *(float4*)&p.aEz[g] = make_float4(ez[a][0], ez[a][1], ez[a][2], ez[a][3]);
        *(float4*)&p.aEo[g] = make_float4(eo[a][0], eo[a][1], eo[a][2], eo[a][3]);
        *(float4*)&p.aJz[g] = make_float4(jz[a][0], jz[a][1], jz[a][2], jz[a][3]);
        *(float4*)&p.aJo[g] = make_float4(jo[a][0], jo[a][1], jo[a][2], jo[a][3]);
        *(float4*)&p.aHx[g] = make_float4(hx[a][0], hx[a][1], hx[a][2], hx[a][3]);
        *(float4*)&p.aHy[g] = make_float4(hy[a][0], hy[a][1], hy[a][2], hy[a][3]);
    }
}

// ---------------------------------------------------------------------------
// One temporal-blocked phase (Kt=8 steps), ONE barrier per step.
// 24x24 threads x 2x2 cells = 48x48 tile, owned 32x32 -> redundancy 2.25x.
// Ez is the only field exchanged through LDS (parity-double-buffered tile;
// the single barrier per step is WAR-safe). Zero-ring LDS -> unconditional
// neighbor reads. Own-H and Lorentz terms phi/base/pj hoisted pre-barrier.
// Ghost H registers (up-row hyU, left-col hxL) updated redundantly.
// writeOut: last phase writes its owned Ez directly to the dense output.
// ---------------------------------------------------------------------------
__global__ __launch_bounds__(NTHR)
void phase_kernel(PParams p, int t, int b0, float* __restrict__ out,
                  int writeOut)
{
    __shared__ __align__(16) float sEz[2][LROWS][SPITCH];

    const int tid = threadIdx.x;
    const int ti = tid / TDIM, tj = tid - ti * TDIM;
    const int li0 = 2 * ti, lj0 = 2 * tj;

    // Bijective XCD-chunked swizzle (grid is always square).
    const int gx = (int)gridDim.x;
    int orig = (int)blockIdx.y * gx + (int)blockIdx.x;
    int nwg = gx * gx;
    int q = nwg >> 3, rr = nwg & 7;
    int xcd = orig & 7, kk = orig >> 3;
    int nid = (xcd < rr ? xcd * (q + 1) : rr * (q + 1) + (xcd - rr) * q) + kk;
    int bx = nid % gx, by = nid / gx;

    const int r0 = (bx + b0) * Bt + li0;  // padded row, cell(0,*)
    const int c0 = (by + b0) * Bt + lj0;  // padded col, cell(*,0)

    const float ca = p.Caa[0], cb = p.Cba[0], cc = p.Cca[0];
    const float cd = p.Cda[0], ce = p.Cea[0];
    const float ca1 = ca + 1.0f;
    const float C1 = p.C1a[0], C2 = p.C2a[0];
    const float cbdx = p.Cbdxa[0], cbdy = p.Cbdya[0];
    const float dbhx0 = p.dbhxa[0], dbhy0 = p.dbhya[0];

    float dHx[2][2], dHy[2][2], dE[2][2], dHyU[2], dHxL[2];
    float srcw[2][2];
#pragma unroll
    for (int a = 0; a < 2; ++a)
#pragma unroll
        for (int b = 0; b < 2; ++b) {
            dHx[a][b] = p.aexP[r0 + a] * p.ahyP[c0 + b];
            dHy[a][b] = p.ahxP[r0 + a] * p.aeyP[c0 + b];
            dE[a][b]  = p.dexP[r0 + a] * p.deyP[c0 + b];
            srcw[a][b] = ((r0 + a == CP) && (c0 + b == CP)) ? 1.0f : 0.0f;
        }
    {
        float ahxU = (r0 > 0) ? p.ahxP[r0 - 1] : 0.0f;   // table idx guard
        float ahyL = (c0 > 0) ? p.ahyP[c0 - 1] : 0.0f;
        dHyU[0] = ahxU * p.aeyP[c0];
        dHyU[1] = ahxU * p.aeyP[c0 + 1];
        dHxL[0] = p.aexP[r0] * ahyL;
        dHxL[1] = p.aexP[r0 + 1] * ahyL;
    }

    const bool odd = (t & 1) != 0;
    const float* cEz = odd ? p.bEz : p.aEz;
    const float* cEo = odd ? p.bEo : p.aEo;
    const float* cJz = odd ? p.bJz : p.aJz;
    const float* cJo = odd ? p.bJo : p.aJo;
    const float* cHx = odd ? p.bHx : p.aHx;
    const float* cHy = odd ? p.bHy : p.aHy;
    float* nEz = odd ? p.aEz : p.bEz;
    float* nEo = odd ? p.aEo : p.bEo;
    float* nJz = odd ? p.aJz : p.bJz;
    float* nJo = odd ? p.aJo : p.bJo;
    float* nHx = odd ? p.aHx : p.bHx;
    float* nHy = odd ? p.aHy : p.bHy;

    // Zero the whole LDS tile once (covers the permanent ring).
    {
        float* sp = &sEz[0][0][0];
        for (int z = tid; z < 2 * LROWS * SPITCH; z += NTHR) sp[z] = 0.0f;
    }

    // Load 2x2 register state (unconditional padded float2)
    float ez[2][2], eo[2][2], jz[2][2], jo[2][2], hx[2][2], hy[2][2];
#pragma unroll
    for (int a = 0; a < 2; ++a) {
        int g = (r0 + a) * PP + c0;
        float2 v;
        v = *(const float2*)&cEz[g]; ez[a][0] = v.x; ez[a][1] = v.y;
        v = *(const float2*)&cEo[g]; eo[a][0] = v.x; eo[a][1] = v.y;
        v = *(const float2*)&cJz[g]; jz[a][0] = v.x; jz[a][1] = v.y;
        v = *(const float2*)&cJo[g]; jo[a][0] = v.x; jo[a][1] = v.y;
        v = *(const float2*)&cHx[g]; hx[a][0] = v.x; hx[a][1] = v.y;
        v = *(const float2*)&cHy[g]; hy[a][0] = v.x; hy[a][1] = v.y;
    }
    // Ghost H (row above / col left); guard row + zero pads make -1 safe
    float hyU[2], hxL[2];
    {
        float2 v = *(const float2*)&cHy[(r0 - 1) * PP + c0];
        hyU[0] = v.x; hyU[1] = v.y;
        hxL[0] = cHx[r0 * PP + c0 - 1];
        hxL[1] = cHx[(r0 + 1) * PP + c0 - 1];
    }

    // Preload the phase's Kt source values (wave-uniform -> SGPR scalar loads)
    const int n0 = t * Kt;
    float svl[Kt];
#pragma unroll
    for (int s = 0; s < Kt; ++s) svl[s] = p.src[n0 + s];

    __syncthreads();   // orders the LDS zero pass before step-0 publishes

    for (int s = 0; s < Kt; ++s) {
        float (*S)[SPITCH] = sEz[s & 1];
        // publish all 4 Ez cells into the ring-padded interior
        *(float2*)&S[1 + li0][2 + lj0] = make_float2(ez[0][0], ez[0][1]);
        *(float2*)&S[2 + li0][2 + lj0] = make_float2(ez[1][0], ez[1][1]);

        // ---- own-only H components BEFORE the barrier (overlap the wait) ----
        hx[0][0] = dHx[0][0] * (hx[0][0] - dbhx0 * (ez[0][1] - ez[0][0]));
        hx[1][0] = dHx[1][0] * (hx[1][0] - dbhx0 * (ez[1][1] - ez[1][0]));
        hy[0][0] = dHy[0][0] * (hy[0][0] + dbhy0 * (ez[1][0] - ez[0][0]));
        hy[0][1] = dHy[0][1] * (hy[0][1] + dbhy0 * (ez[1][1] - ez[0][1]));

        // ---- Lorentz recursion terms: no neighbor deps -> pre-barrier ----
        float base[2][2], pj[2][2];
#pragma unroll
        for (int a = 0; a < 2; ++a)
#pragma unroll
            for (int b = 0; b < 2; ++b) {
                float e = ez[a][b], j = jz[a][b];
                float phi = ca1 * j + cb * jo[a][b] + cd * e + ce * eo[a][b];
                base[a][b] = fmaf(-C2, phi, C1 * e);
                pj[a][b] = phi - j;
            }

        __syncthreads();

        // Unconditional neighbor reads; tile-edge reads hit the zero ring.
        float eR0 = S[1 + li0][4 + lj0];
        float eR1 = S[2 + li0][4 + lj0];
        float2 eD = *(float2*)&S[3 + li0][2 + lj0];
        float2 eU = *(float2*)&S[li0][2 + lj0];
        float eL0 = S[1 + li0][1 + lj0];
        float eL1 = S[2 + li0][1 + lj0];

        // ---- remaining H components (need neighbor Ez) ----
        hx[0][1] = dHx[0][1] * (hx[0][1] - dbhx0 * (eR0 - ez[0][1]));
        hx[1][1] = dHx[1][1] * (hx[1][1] - dbhx0 * (eR1 - ez[1][1]));
        hy[1][0] = dHy[1][0] * (hy[1][0] + dbhy0 * (eD.x - ez[1][0]));
        hy[1][1] = dHy[1][1] * (hy[1][1] + dbhy0 * (eD.y - ez[1][1]));

        // ---- ghost H update (same arithmetic as the neighbor's own) ----
        hyU[0] = dHyU[0] * (hyU[0] + dbhy0 * (ez[0][0] - eU.x));
        hyU[1] = dHyU[1] * (hyU[1] + dbhy0 * (ez[0][1] - eU.y));
        hxL[0] = dHxL[0] * (hxL[0] - dbhx0 * (ez[0][0] - eL0));
        hxL[1] = dHxL[1] * (hxL[1] - dbhx0 * (ez[1][0] - eL1));

        // ---- E update (short post-barrier chain) ----
        float sv = svl[s];
        float cHyv[2][2], cHxv[2][2];
        cHyv[0][0] = hy[0][0] - hyU[0];   cHxv[0][0] = hx[0][0] - hxL[0];
        cHyv[0][1] = hy[0][1] - hyU[1];   cHxv[0][1] = hx[0][1] - hx[0][0];
        cHyv[1][0] = hy[1][0] - hy[0][0]; cHxv[1][0] = hx[1][0] - hxL[1];
        cHyv[1][1] = hy[1][1] - hy[0][1]; cHxv[1][1] = hx[1][1] - hx[1][0];

#pragma unroll
        for (int a = 0; a < 2; ++a)
#pragma unroll
            for (int b = 0; b < 2; ++b) {
                float v1 = fmaf(cbdx, cHyv[a][b], base[a][b]);
                float v2 = fmaf(-cbdy, cHxv[a][b], v1);
                float en = dE[a][b] * v2;
                en = fmaf(srcw[a][b], sv, en);   // source after mask*de
                float jn = fmaf(cc, en, pj[a][b]);
                eo[a][b] = ez[a][b];  ez[a][b] = en;
                jo[a][b] = jz[a][b];  jz[a][b] = jn;
            }
        // Single barrier per step: next iteration stores to the OTHER LDS
        // buffer (parity), so late readers of this buffer are safe.
    }

    // store owned interior [Kt, Kt+Bt)^2 -> ti,tj in [OWN_T0, OWN_T1)
    if (ti >= OWN_T0 && ti < OWN_T1 && tj >= OWN_T0 && tj < OWN_T1) {
#pragma unroll
        for (int a = 0; a < 2; ++a) {
            int g = (r0 + a) * PP + c0;
            *(float2*)&nEz[g] = make_float2(ez[a][0], ez[a][1]);
            *(float2*)&nEo[g] = make_float2(eo[a][0], eo[a][1]);
            *(float2*)&nJz[g] = make_float2(jz[a][0], jz[a][1]);
            *(float2*)&nJo[g] = make_float2(jo[a][0], jo[a][1]);
            *(float2*)&nHx[g] = make_float2(hx[a][0], hx[a][1]);
            *(float2*)&nHy[g] = make_float2(hy[a][0], hy[a][1]);
        }
        // Last phase: owned regions tile the padded domain exactly; emit the
        // dense 421x421 output directly (same register values copy_out read).
        if (writeOut) {
#pragma unroll
            for (int a = 0; a < 2; ++a)
#pragma unroll
                for (int b = 0; b < 2; ++b) {
                    int gi = r0 + a - PAD, gj = c0 + b - PAD;  // >= 0 (owned)
                    if (gi < NXr && gj < NXr)
                        out[gi * NXr + gj] = ez[a][b];
                }
        }
    }
}

// ---------------------------------------------------------------------------
extern "C" void kernel_launch(void* const* d_in, const int* in_sizes, int n_in,
                              void* d_out, int out_size, void* d_ws, size_t ws_size,
                              hipStream_t stream)
{
    const float* src    = (const float*)d_in[0];
    const float* C1     = (const float*)d_in[1];
    const float* C2     = (const float*)d_in[2];
    const float* Cb_dx  = (const float*)d_in[3];
    const float* Cb_dy  = (const float*)d_in[4];
    const float* dbhx   = (const float*)d_in[5];
    const float* dbhy   = (const float*)d_in[6];
    const float* Ca     = (const float*)d_in[7];
    const float* Cb     = (const float*)d_in[8];
    const float* Cc     = (const float*)d_in[9];
    const float* Cd     = (const float*)d_in[10];
    const float* Ce     = (const float*)d_in[11];
    const float* sig_ex = (const float*)d_in[12];
    const float* sig_ey = (const float*)d_in[13];
    const float* sig_hx = (const float*)d_in[14];
    const float* sig_hy = (const float*)d_in[15];
    // d_in[16] = n_steps (always 200) — hard-coded for graph capture.

    const double EPS0 = 1e-9 / 36.0 / M_PI;
    const double MU0  = 4.0 * M_PI * 1e-7;
    const double C0   = 1.0 / sqrt(MU0 * EPS0);
    const double DXd  = 2.5e-8, DYd = 2.5e-8;
    const double DT   = 0.99 / C0 / sqrt(1.0 / (DXd * DXd) + 1.0 / (DYd * DYd));
    const float de_fac = (float)(DT / EPS0);
    const float dh_fac = (float)(DT / MU0);

    // Workspace: [guard row PP] [12 padded fields] [6 padded tables] (~10.3 MB)
    float* base = (float*)d_ws;
    float* fields = base + PP;
    float* w = fields + 12 * (size_t)FSZ;
    float* dexP = w; w += PP;
    float* deyP = w; w += PP;
    float* aexP = w; w += PP;
    float* aeyP = w; w += PP;
    float* ahxP = w; w += PP;
    float* ahyP = w; w += PP;

    PParams p;
    p.aEz = fields + 0 * (size_t)FSZ;  p.aEo = fields + 1 * (size_t)FSZ;
    p.aJz = fields + 2 * (size_t)FSZ;  p.aJo = fields + 3 * (size_t)FSZ;
    p.aHx = fields + 4 * (size_t)FSZ;  p.aHy = fields + 5 * (size_t)FSZ;
    p.bEz = fields + 6 * (size_t)FSZ;  p.bEo = fields + 7 * (size_t)FSZ;
    p.bJz = fields + 8 * (size_t)FSZ;  p.bJo = fields + 9 * (size_t)FSZ;
    p.bHx = fields + 10 * (size_t)FSZ; p.bHy = fields + 11 * (size_t)FSZ;
    p.dexP = dexP; p.deyP = deyP; p.aexP = aexP; p.aeyP = aeyP;
    p.ahxP = ahxP; p.ahyP = ahyP;
    p.C1a = C1; p.C2a = C2; p.Cbdxa = Cb_dx; p.Cbdya = Cb_dy;
    p.Caa = Ca; p.Cba = Cb; p.Cca = Cc; p.Cda = Cd; p.Cea = Ce;
    p.dbhxa = dbhx; p.dbhya = dbhy;
    p.src = src;

    init_kernel<<<512, 256, 0, stream>>>(sig_ex, sig_ey, sig_hx, sig_hy,
                                         de_fac, dh_fac,
                                         base, PP + 12 * FSZ,
                                         dexP, deyP, aexP, aeyP, ahxP, ahyP);

    // Steps 0..31 in one zero-redundancy single-block dispatch. Writes set A.
    seed_kernel<<<1, 256, 0, stream>>>(p);

    // Phases t=4..24: 21 x 8 steps (steps 32..199).
    dim3 blk(NTHR);
    for (int t = 4; t <= 24; ++t) {
        // Support bound: after n steps the field is confined to a Chebyshev
        // ball of radius n-1 around the source. End of phase t is step 8(t+1)
        // -> radius 8t+7. Tile-extent gate with R = 8t+11 keeps >= +4 margin
        // (and the owned-region criterion adds more slack). Launch sets are
        // monotone in t -> the ping-pong skip stays exact. t-only formula ->
        // identical grids every call (capture-safe).
        int R  = 8 * t + 11;
        int lo = CP - R, hi = CP + R;
        int b0 = (lo - (EXT - 1)) / Bt; if (b0 < 0) b0 = 0;
        int b1 = hi / Bt;               if (b1 > NBLK - 1) b1 = NBLK - 1;
        dim3 g(b1 - b0 + 1, b1 - b0 + 1);
        phase_kernel<<<g, blk, 0, stream>>>(p, t, b0, (float*)d_out,
                                            (t == 24) ? 1 : 0);
    }
    // No copy_out dispatch: phase t=24 wrote the dense output directly.
}

// Round 6
// 251.043 us; speedup vs baseline: 1.1580x; 1.1580x over previous
//
#include <hip/hip_runtime.h>
#include <math.h>

// Real grid (match reference): 421 x 421 E-grid, source at (210,210)
#define NXr 421
#define CXr 210
#define NSTEPS_C 200

// Round 17 = R12 champion structure VERBATIM (Kt=8/Bt=16/EXT=32, 256 thr,
// 26 dispatches, 256.6 us) with ONE change: the step body uses packed
// dual-FP32 (ext_vector_type(2) -> v_pk_fma_f32/v_pk_mul_f32 on CDNA4).
// The 2x2-cell layout packs along the column pair (b=0,1): H-row updates,
// Lorentz recursion, curls and the E-update are elementwise in b. Only the
// hx shift (needs ez[b+1]) and the left-ghost scalars stay unpacked.
// R13-R16 (263/258/283/291) bracket R12 geometrically from every direction:
// geometry is exhausted; ~55% of late-phase time is VALU issue -> halve it.
#define Bt   16
#define Kt   8
#define EXT  32
#define LROWS (EXT + 2)            // 34: zero ring row above/below
#define SPITCH 36                  // 2+32+2 cols, even => float2-aligned interior
#define NBLK 27                    // 27*16 = 432 computational domain
#define NPHASE (NSTEPS_C / Kt)     // 25

// Padded zero-ring layout: fields are PP x PP with the computational domain
// [0,432)^2 at offset (PAD,PAD). Coefficient tables are zero outside the real
// 421^2 domain, so cells outside it provably stay 0 forever -> all hot
// loads/stores are unconditional float2. A zeroed guard row (PP floats) sits
// in front of the field block so ghost loads at padded row/col -1 are safe.
#define PP   448
#define PAD  8
#define CP   (CXr + PAD)           // source in padded coords: 218
#define FSZ  (PP * PP)             // floats per padded field

typedef float v2f __attribute__((ext_vector_type(2)));
static __device__ __forceinline__ v2f mk2(float x, float y)
{ v2f r; r.x = x; r.y = y; return r; }

struct PParams {
    float *aEz, *aEo, *aJz, *aJo, *aHx, *aHy;   // state set A
    float *bEz, *bEo, *bJz, *bJo, *bHx, *bHy;   // state set B
    const float *dexP, *deyP, *aexP, *aeyP, *ahxP, *ahyP;  // padded 1-D tables
    const float *C1a, *C2a, *Cbdxa, *Cbdya;
    const float *Caa, *Cba, *Cca, *Cda, *Cea, *dbhxa, *dbhya;
    const float *src;
};

// ---------------------------------------------------------------------------
// Init: zero guard row + both padded state sets; build padded coeff tables.
// dexP/deyP fold the interior mask (nonzero only for real coords 1..419).
// Zeroing BOTH sets every call keeps the support-gating skip exact.
// ---------------------------------------------------------------------------
__global__ void init_kernel(const float* __restrict__ sig_ex,
                            const float* __restrict__ sig_ey,
                            const float* __restrict__ sig_hx,
                            const float* __restrict__ sig_hy,
                            float de_fac, float dh_fac,
                            float* __restrict__ zero_base, int n_zero,
                            float* __restrict__ dexP, float* __restrict__ deyP,
                            float* __restrict__ aexP, float* __restrict__ aeyP,
                            float* __restrict__ ahxP, float* __restrict__ ahyP)
{
    int t = blockIdx.x * blockDim.x + threadIdx.x;
    int stride = gridDim.x * blockDim.x;
    for (int k = t; k < n_zero; k += stride) zero_base[k] = 0.0f;
    if (t < PP) {
        int g = t - PAD;
        dexP[t] = (g >= 1 && g <= NXr - 2) ? expf(-sig_ex[g] * de_fac) : 0.0f;
        deyP[t] = (g >= 1 && g <= NXr - 2) ? expf(-sig_ey[g] * de_fac) : 0.0f;
        aexP[t] = (g >= 0 && g <  NXr)     ? expf(-sig_ex[g] * dh_fac) : 0.0f;
        aeyP[t] = (g >= 0 && g <  NXr)     ? expf(-sig_ey[g] * dh_fac) : 0.0f;
        ahxP[t] = (g >= 0 && g <  NXr - 1) ? expf(-sig_hx[g] * dh_fac) : 0.0f;
        ahyP[t] = (g >= 0 && g <  NXr - 1) ? expf(-sig_hy[g] * dh_fac) : 0.0f;
    }
}

// ---------------------------------------------------------------------------
// One temporal-blocked phase (Kt=8 steps), ONE barrier per step.
// Ez is the only field exchanged through LDS (parity-double-buffered tile:
// step s+1 stores to the other buffer, so the single barrier is WAR-safe).
// The LDS tile carries a permanent zero ring, zeroed once pre-loop, so every
// neighbor read is unconditional; tile-edge reads see 0 exactly as edge
// selects would. Up/left neighbor H values are ghost registers updated
// redundantly from the exchanged Ez (identical arithmetic to the neighbor's).
// All row-wise arithmetic is v2f packed (column pair b=0,1) -> v_pk_* ops.
// writeOut: last phase writes its owned Ez directly to the dense output.
// ---------------------------------------------------------------------------
__global__ __launch_bounds__(256)
void phase_kernel(PParams p, int t, int b0, float* __restrict__ out,
                  int writeOut)
{
    __shared__ __align__(16) float sEz[2][LROWS][SPITCH];

    const int tid = threadIdx.x;
    const int tj = tid & 15, ti = tid >> 4;
    const int li0 = 2 * ti, lj0 = 2 * tj;

    // Bijective XCD-chunked swizzle (grid is always square). Pure permutation.
    const int gx = (int)gridDim.x;
    int orig = (int)blockIdx.y * gx + (int)blockIdx.x;
    int nwg = gx * gx;
    int q = nwg >> 3, rr = nwg & 7;
    int xcd = orig & 7, kk = orig >> 3;
    int nid = (xcd < rr ? xcd * (q + 1) : rr * (q + 1) + (xcd - rr) * q) + kk;
    int bx = nid % gx, by = nid / gx;

    const int r0 = (bx + b0) * Bt + li0;  // padded row, cell(0,*)
    const int c0 = (by + b0) * Bt + lj0;  // padded col, cell(*,0)

    const float ca = p.Caa[0], cb = p.Cba[0], cc = p.Cca[0];
    const float cd = p.Cda[0], ce = p.Cea[0];
    const float ca1f = ca + 1.0f;
    const float C1f = p.C1a[0], C2f = p.C2a[0];
    const float cbdxf = p.Cbdxa[0], cbdyf = p.Cbdya[0];
    const float dbhx0 = p.dbhxa[0], dbhy0 = p.dbhya[0];

    // Packed splat constants
    const v2f vca1 = mk2(ca1f, ca1f), vcb = mk2(cb, cb), vcc = mk2(cc, cc);
    const v2f vcd = mk2(cd, cd), vce = mk2(ce, ce);
    const v2f vC1 = mk2(C1f, C1f), vC2 = mk2(C2f, C2f);
    const v2f vbx = mk2(cbdxf, cbdxf), vby = mk2(cbdyf, cbdyf);
    const v2f vhx = mk2(dbhx0, dbhx0), vhy = mk2(dbhy0, dbhy0);

    // Per-cell damping products (interior mask folded into dE) + ghost damping
    v2f dHx[2], dHy[2], dE[2], dHyU, srcw[2];
    float dHxL[2];
#pragma unroll
    for (int a = 0; a < 2; ++a) {
        float aex = p.aexP[r0 + a], ahxv = p.ahxP[r0 + a], dex = p.dexP[r0 + a];
        dHx[a] = mk2(aex * p.ahyP[c0], aex * p.ahyP[c0 + 1]);
        dHy[a] = mk2(ahxv * p.aeyP[c0], ahxv * p.aeyP[c0 + 1]);
        dE[a]  = mk2(dex * p.deyP[c0], dex * p.deyP[c0 + 1]);
        srcw[a] = mk2(((r0 + a == CP) && (c0 == CP)) ? 1.0f : 0.0f,
                      ((r0 + a == CP) && (c0 + 1 == CP)) ? 1.0f : 0.0f);
    }
    {
        float ahxU = (r0 > 0) ? p.ahxP[r0 - 1] : 0.0f;   // table idx guard
        float ahyL = (c0 > 0) ? p.ahyP[c0 - 1] : 0.0f;
        dHyU = mk2(ahxU * p.aeyP[c0], ahxU * p.aeyP[c0 + 1]);
        dHxL[0] = p.aexP[r0] * ahyL;
        dHxL[1] = p.aexP[r0 + 1] * ahyL;
    }

    const bool odd = (t & 1) != 0;
    const float* cEz = odd ? p.bEz : p.aEz;
    const float* cEo = odd ? p.bEo : p.aEo;
    const float* cJz = odd ? p.bJz : p.aJz;
    const float* cJo = odd ? p.bJo : p.aJo;
    const float* cHx = odd ? p.bHx : p.aHx;
    const float* cHy = odd ? p.bHy : p.aHy;
    float* nEz = odd ? p.aEz : p.bEz;
    float* nEo = odd ? p.aEo : p.bEo;
    float* nJz = odd ? p.aJz : p.bJz;
    float* nJo = odd ? p.aJo : p.bJo;
    float* nHx = odd ? p.aHx : p.bHx;
    float* nHy = odd ? p.aHy : p.bHy;

    // Zero the whole LDS tile once (covers the permanent ring). Must be
    // barrier-separated from the step-0 interior publishes (same addresses).
    {
        float* sp = &sEz[0][0][0];
        for (int z = tid; z < 2 * LROWS * SPITCH; z += 256) sp[z] = 0.0f;
    }

    // Load 2x2 register state (unconditional padded float2) as packed rows
    v2f ez[2], eo[2], jz[2], jo[2], hx[2], hy[2];
#pragma unroll
    for (int a = 0; a < 2; ++a) {
        int g = (r0 + a) * PP + c0;
        float2 v;
        v = *(const float2*)&cEz[g]; ez[a] = mk2(v.x, v.y);
        v = *(const float2*)&cEo[g]; eo[a] = mk2(v.x, v.y);
        v = *(const float2*)&cJz[g]; jz[a] = mk2(v.x, v.y);
        v = *(const float2*)&cJo[g]; jo[a] = mk2(v.x, v.y);
        v = *(const float2*)&cHx[g]; hx[a] = mk2(v.x, v.y);
        v = *(const float2*)&cHy[g]; hy[a] = mk2(v.x, v.y);
    }
    // Ghost H (row above / col left); guard row + zero pads make -1 safe
    v2f hyU;
    float hxL[2];
    {
        float2 v = *(const float2*)&cHy[(r0 - 1) * PP + c0];
        hyU = mk2(v.x, v.y);
        hxL[0] = cHx[r0 * PP + c0 - 1];
        hxL[1] = cHx[(r0 + 1) * PP + c0 - 1];
    }

    // Preload the phase's Kt source values (wave-uniform -> SGPR scalar loads)
    const int n0 = t * Kt;
    float svl[Kt];
#pragma unroll
    for (int s = 0; s < Kt; ++s) svl[s] = p.src[n0 + s];

    __syncthreads();   // orders the LDS zero pass before step-0 publishes

    for (int s = 0; s < Kt; ++s) {
        float (*S)[SPITCH] = sEz[s & 1];
        // publish all 4 Ez cells into the ring-padded interior
        *(float2*)&S[1 + li0][2 + lj0] = make_float2(ez[0].x, ez[0].y);
        *(float2*)&S[2 + li0][2 + lj0] = make_float2(ez[1].x, ez[1].y);

        // ---- pre-barrier (no neighbor deps): hy[0] + Lorentz recursion ----
        hy[0] = dHy[0] * (hy[0] + vhy * (ez[1] - ez[0]));

        v2f phi0 = vca1 * jz[0] + vcb * jo[0] + vcd * ez[0] + vce * eo[0];
        v2f phi1 = vca1 * jz[1] + vcb * jo[1] + vcd * ez[1] + vce * eo[1];
        v2f base0 = vC1 * ez[0] - vC2 * phi0;
        v2f base1 = vC1 * ez[1] - vC2 * phi1;
        v2f pj0 = phi0 - jz[0];
        v2f pj1 = phi1 - jz[1];

        __syncthreads();

        // Unconditional neighbor reads; tile-edge reads hit the zero ring.
        float eR0 = S[1 + li0][4 + lj0];
        float eR1 = S[2 + li0][4 + lj0];
        float2 eDf = *(float2*)&S[3 + li0][2 + lj0];
        float2 eUf = *(float2*)&S[li0][2 + lj0];
        float eL0 = S[1 + li0][1 + lj0];
        float eL1 = S[2 + li0][1 + lj0];
        v2f eD = mk2(eDf.x, eDf.y), eU = mk2(eUf.x, eUf.y);

        // ---- H updates (packed rows; hx needs the column-shifted ez) ----
        v2f sh0 = mk2(ez[0].y, eR0);
        v2f sh1 = mk2(ez[1].y, eR1);
        hx[0] = dHx[0] * (hx[0] - vhx * (sh0 - ez[0]));
        hx[1] = dHx[1] * (hx[1] - vhx * (sh1 - ez[1]));
        hy[1] = dHy[1] * (hy[1] + vhy * (eD - ez[1]));

        // ---- ghost H update (same arithmetic as the neighbor's own) ----
        hyU = dHyU * (hyU + vhy * (ez[0] - eU));
        hxL[0] = dHxL[0] * (hxL[0] - dbhx0 * (ez[0].x - eL0));
        hxL[1] = dHxL[1] * (hxL[1] - dbhx0 * (ez[1].x - eL1));

        // ---- curls (packed) ----
        v2f cHy0 = hy[0] - hyU;
        v2f cHy1 = hy[1] - hy[0];
        v2f cHx0 = hx[0] - mk2(hxL[0], hx[0].x);
        v2f cHx1 = hx[1] - mk2(hxL[1], hx[1].x);

        // ---- E update (packed short chain) ----
        float sv = svl[s];
        v2f vsv = mk2(sv, sv);
        v2f en0 = dE[0] * (base0 + vbx * cHy0 - vby * cHx0) + srcw[0] * vsv;
        v2f en1 = dE[1] * (base1 + vbx * cHy1 - vby * cHx1) + srcw[1] * vsv;
        v2f jn0 = pj0 + vcc * en0;
        v2f jn1 = pj1 + vcc * en1;

        eo[0] = ez[0]; ez[0] = en0;
        eo[1] = ez[1]; ez[1] = en1;
        jo[0] = jz[0]; jz[0] = jn0;
        jo[1] = jz[1]; jz[1] = jn1;
        // Single barrier per step: next iteration stores to the OTHER LDS
        // buffer (parity), so late readers of this buffer are safe.
    }

    // store owned interior [Kt, Kt+Bt)^2 -> ti,tj in [4,12)
    if (ti >= 4 && ti < 12 && tj >= 4 && tj < 12) {
#pragma unroll
        for (int a = 0; a < 2; ++a) {
            int g = (r0 + a) * PP + c0;
            *(float2*)&nEz[g] = make_float2(ez[a].x, ez[a].y);
            *(float2*)&nEo[g] = make_float2(eo[a].x, eo[a].y);
            *(float2*)&nJz[g] = make_float2(jz[a].x, jz[a].y);
            *(float2*)&nJo[g] = make_float2(jo[a].x, jo[a].y);
            *(float2*)&nHx[g] = make_float2(hx[a].x, hx[a].y);
            *(float2*)&nHy[g] = make_float2(hy[a].x, hy[a].y);
        }
        // Last phase: owned regions tile the padded domain exactly; emit the
        // dense 421x421 output directly (same register values copy_out read).
        if (writeOut) {
#pragma unroll
            for (int a = 0; a < 2; ++a) {
                int gi = r0 + a - PAD;
                if (gi < NXr) {
                    int gj = c0 - PAD;
                    if (gj < NXr)     out[gi * NXr + gj]     = ez[a].x;
                    if (gj + 1 < NXr) out[gi * NXr + gj + 1] = ez[a].y;
                }
            }
        }
    }
}

// ---------------------------------------------------------------------------
extern "C" void kernel_launch(void* const* d_in, const int* in_sizes, int n_in,
                              void* d_out, int out_size, void* d_ws, size_t ws_size,
                              hipStream_t stream)
{
    const float* src    = (const float*)d_in[0];
    const float* C1     = (const float*)d_in[1];
    const float* C2     = (const float*)d_in[2];
    const float* Cb_dx  = (const float*)d_in[3];
    const float* Cb_dy  = (const float*)d_in[4];
    const float* dbhx   = (const float*)d_in[5];
    const float* dbhy   = (const float*)d_in[6];
    const float* Ca     = (const float*)d_in[7];
    const float* Cb     = (const float*)d_in[8];
    const float* Cc     = (const float*)d_in[9];
    const float* Cd     = (const float*)d_in[10];
    const float* Ce     = (const float*)d_in[11];
    const float* sig_ex = (const float*)d_in[12];
    const float* sig_ey = (const float*)d_in[13];
    const float* sig_hx = (const float*)d_in[14];
    const float* sig_hy = (const float*)d_in[15];
    // d_in[16] = n_steps (always 200) — hard-coded for graph capture.

    const double EPS0 = 1e-9 / 36.0 / M_PI;
    const double MU0  = 4.0 * M_PI * 1e-7;
    const double C0   = 1.0 / sqrt(MU0 * EPS0);
    const double DXd  = 2.5e-8, DYd = 2.5e-8;
    const double DT   = 0.99 / C0 / sqrt(1.0 / (DXd * DXd) + 1.0 / (DYd * DYd));
    const float de_fac = (float)(DT / EPS0);
    const float dh_fac = (float)(DT / MU0);

    // Workspace: [guard row PP] [12 padded fields] [6 padded tables] (~10 MB)
    float* base = (float*)d_ws;
    float* fields = base + PP;
    float* w = fields + 12 * (size_t)FSZ;
    float* dexP = w; w += PP;
    float* deyP = w; w += PP;
    float* aexP = w; w += PP;
    float* aeyP = w; w += PP;
    float* ahxP = w; w += PP;
    float* ahyP = w; w += PP;

    PParams p;
    p.aEz = fields + 0 * (size_t)FSZ;  p.aEo = fields + 1 * (size_t)FSZ;
    p.aJz = fields + 2 * (size_t)FSZ;  p.aJo = fields + 3 * (size_t)FSZ;
    p.aHx = fields + 4 * (size_t)FSZ;  p.aHy = fields + 5 * (size_t)FSZ;
    p.bEz = fields + 6 * (size_t)FSZ;  p.bEo = fields + 7 * (size_t)FSZ;
    p.bJz = fields + 8 * (size_t)FSZ;  p.bJo = fields + 9 * (size_t)FSZ;
    p.bHx = fields + 10 * (size_t)FSZ; p.bHy = fields + 11 * (size_t)FSZ;
    p.dexP = dexP; p.deyP = deyP; p.aexP = aexP; p.aeyP = aeyP;
    p.ahxP = ahxP; p.ahyP = ahyP;
    p.C1a = C1; p.C2a = C2; p.Cbdxa = Cb_dx; p.Cbdya = Cb_dy;
    p.Caa = Ca; p.Cba = Cb; p.Cca = Cc; p.Cda = Cd; p.Cea = Ce;
    p.dbhxa = dbhx; p.dbhya = dbhy;
    p.src = src;

    init_kernel<<<512, 256, 0, stream>>>(sig_ex, sig_ey, sig_hx, sig_hy,
                                         de_fac, dh_fac,
                                         base, PP + 12 * FSZ,
                                         dexP, deyP, aexP, aeyP, ahxP, ahyP);

    dim3 blk(256);
    for (int t = 0; t < NPHASE; ++t) {
        // Support bound: after n steps the field is confined to a Chebyshev
        // ball of radius n-1 around the source. End of phase t is step 8(t+1)
        // -> radius 8t+7. Tile-based gate with R = 8t+11 has >= +10 margin
        // over the owned-region criterion. Launch sets are monotone in t ->
        // the ping-pong skip stays exact. t-only formula -> identical grids
        // every call (capture-safe).
        int R  = 8 * t + 11;
        int lo = CP - R, hi = CP + R;
        int b0 = (lo - (EXT - 1)) / 16; if (b0 < 0) b0 = 0;
        int b1 = hi / 16;               if (b1 > NBLK - 1) b1 = NBLK - 1;
        dim3 g(b1 - b0 + 1, b1 - b0 + 1);
        phase_kernel<<<g, blk, 0, stream>>>(p, t, b0, (float*)d_out,
                                            (t == NPHASE - 1) ? 1 : 0);
    }
    // No copy_out dispatch: phase t=24 wrote the dense output directly.
}

// Round 7
// 246.376 us; speedup vs baseline: 1.1799x; 1.0189x over previous
//
#include <hip/hip_runtime.h>
#include <math.h>

// Real grid (match reference): 421 x 421 E-grid, source at (210,210)
#define NXr 421
#define CXr 210
#define NSTEPS_C 200

// Round 18 = R17 (packed v2f body, 251.0 us) with the STATE REDUCTION:
// (Ez, Eold, Jz, Jold, Hx, Hy) -> (Ez, Jz, U, Hx, Hy) where
//   u   = cb*Jold + ce*Eold        (carried instead of Jold/Eold)
//   phi = (ca+1)*J + cd*E + u
//   Jn  = phi - J + cc*En
//   u'  = cb*J + ce*E              (pre-update values)
// Same recurrence; 5 fields instead of 6 -> phase prologue loads 6->5,
// epilogue stores 6->5, ~17% less phase-boundary traffic, fewer registers,
// and the eo/jo register shuffles become one mul+fma. Also re-hoists the hx
// partial (w = hx + vhx*ez, no neighbor deps) pre-barrier (lost in R17).
// Everything else identical to R17 (Kt=8/Bt=16/EXT=32, 26 dispatches).
#define Bt   16
#define Kt   8
#define EXT  32
#define LROWS (EXT + 2)            // 34: zero ring row above/below
#define SPITCH 36                  // 2+32+2 cols, even => float2-aligned interior
#define NBLK 27                    // 27*16 = 432 computational domain
#define NPHASE (NSTEPS_C / Kt)     // 25

// Padded zero-ring layout: fields are PP x PP with the computational domain
// [0,432)^2 at offset (PAD,PAD). Coefficient tables are zero outside the real
// 421^2 domain, so cells outside it provably stay 0 forever -> all hot
// loads/stores are unconditional float2 (u: cb*0+ce*0 = 0 preserved). A
// zeroed guard row (PP floats) sits in front of the field block so ghost
// loads at padded row/col -1 are safe.
#define PP   448
#define PAD  8
#define CP   (CXr + PAD)           // source in padded coords: 218
#define FSZ  (PP * PP)             // floats per padded field

typedef float v2f __attribute__((ext_vector_type(2)));
static __device__ __forceinline__ v2f mk2(float x, float y)
{ v2f r; r.x = x; r.y = y; return r; }

struct PParams {
    float *aEz, *aJz, *aU, *aHx, *aHy;          // state set A (5 fields)
    float *bEz, *bJz, *bU, *bHx, *bHy;          // state set B
    const float *dexP, *deyP, *aexP, *aeyP, *ahxP, *ahyP;  // padded 1-D tables
    const float *C1a, *C2a, *Cbdxa, *Cbdya;
    const float *Caa, *Cba, *Cca, *Cda, *Cea, *dbhxa, *dbhya;
    const float *src;
};

// ---------------------------------------------------------------------------
// Init: zero guard row + both padded state sets; build padded coeff tables.
// dexP/deyP fold the interior mask (nonzero only for real coords 1..419).
// Zeroing BOTH sets every call keeps the support-gating skip exact.
// ---------------------------------------------------------------------------
__global__ void init_kernel(const float* __restrict__ sig_ex,
                            const float* __restrict__ sig_ey,
                            const float* __restrict__ sig_hx,
                            const float* __restrict__ sig_hy,
                            float de_fac, float dh_fac,
                            float* __restrict__ zero_base, int n_zero,
                            float* __restrict__ dexP, float* __restrict__ deyP,
                            float* __restrict__ aexP, float* __restrict__ aeyP,
                            float* __restrict__ ahxP, float* __restrict__ ahyP)
{
    int t = blockIdx.x * blockDim.x + threadIdx.x;
    int stride = gridDim.x * blockDim.x;
    for (int k = t; k < n_zero; k += stride) zero_base[k] = 0.0f;
    if (t < PP) {
        int g = t - PAD;
        dexP[t] = (g >= 1 && g <= NXr - 2) ? expf(-sig_ex[g] * de_fac) : 0.0f;
        deyP[t] = (g >= 1 && g <= NXr - 2) ? expf(-sig_ey[g] * de_fac) : 0.0f;
        aexP[t] = (g >= 0 && g <  NXr)     ? expf(-sig_ex[g] * dh_fac) : 0.0f;
        aeyP[t] = (g >= 0 && g <  NXr)     ? expf(-sig_ey[g] * dh_fac) : 0.0f;
        ahxP[t] = (g >= 0 && g <  NXr - 1) ? expf(-sig_hx[g] * dh_fac) : 0.0f;
        ahyP[t] = (g >= 0 && g <  NXr - 1) ? expf(-sig_hy[g] * dh_fac) : 0.0f;
    }
}

// ---------------------------------------------------------------------------
// One temporal-blocked phase (Kt=8 steps), ONE barrier per step.
// Ez is the only field exchanged through LDS (parity-double-buffered tile:
// step s+1 stores to the other buffer, so the single barrier is WAR-safe).
// Permanent zero ring in LDS -> unconditional neighbor reads. Pre-barrier:
// publish Ez, hy[0], hx-partial w, and the Lorentz terms phi/base/pj/u'
// (none need neighbors). Post-barrier: 6 LDS reads -> remaining H, ghost H,
// curls, packed E/J update. Ghost H registers updated redundantly with the
// neighbor's own arithmetic. All row-wise math is v2f packed (v_pk_*).
// writeOut: last phase writes its owned Ez directly to the dense output.
// ---------------------------------------------------------------------------
__global__ __launch_bounds__(256)
void phase_kernel(PParams p, int t, int b0, float* __restrict__ out,
                  int writeOut)
{
    __shared__ __align__(16) float sEz[2][LROWS][SPITCH];

    const int tid = threadIdx.x;
    const int tj = tid & 15, ti = tid >> 4;
    const int li0 = 2 * ti, lj0 = 2 * tj;

    // Bijective XCD-chunked swizzle (grid is always square). Pure permutation.
    const int gx = (int)gridDim.x;
    int orig = (int)blockIdx.y * gx + (int)blockIdx.x;
    int nwg = gx * gx;
    int q = nwg >> 3, rr = nwg & 7;
    int xcd = orig & 7, kk = orig >> 3;
    int nid = (xcd < rr ? xcd * (q + 1) : rr * (q + 1) + (xcd - rr) * q) + kk;
    int bx = nid % gx, by = nid / gx;

    const int r0 = (bx + b0) * Bt + li0;  // padded row, cell(0,*)
    const int c0 = (by + b0) * Bt + lj0;  // padded col, cell(*,0)

    const float ca = p.Caa[0], cb = p.Cba[0], cc = p.Cca[0];
    const float cd = p.Cda[0], ce = p.Cea[0];
    const float ca1f = ca + 1.0f;
    const float C1f = p.C1a[0], C2f = p.C2a[0];
    const float cbdxf = p.Cbdxa[0], cbdyf = p.Cbdya[0];
    const float dbhx0 = p.dbhxa[0], dbhy0 = p.dbhya[0];

    // Packed splat constants
    const v2f vca1 = mk2(ca1f, ca1f), vcb = mk2(cb, cb), vcc = mk2(cc, cc);
    const v2f vcd = mk2(cd, cd), vce = mk2(ce, ce);
    const v2f vC1 = mk2(C1f, C1f), vC2 = mk2(C2f, C2f);
    const v2f vbx = mk2(cbdxf, cbdxf), vby = mk2(cbdyf, cbdyf);
    const v2f vhx = mk2(dbhx0, dbhx0), vhy = mk2(dbhy0, dbhy0);

    // Per-cell damping products (interior mask folded into dE) + ghost damping
    v2f dHx[2], dHy[2], dE[2], dHyU, srcw[2];
    float dHxL[2];
#pragma unroll
    for (int a = 0; a < 2; ++a) {
        float aex = p.aexP[r0 + a], ahxv = p.ahxP[r0 + a], dex = p.dexP[r0 + a];
        dHx[a] = mk2(aex * p.ahyP[c0], aex * p.ahyP[c0 + 1]);
        dHy[a] = mk2(ahxv * p.aeyP[c0], ahxv * p.aeyP[c0 + 1]);
        dE[a]  = mk2(dex * p.deyP[c0], dex * p.deyP[c0 + 1]);
        srcw[a] = mk2(((r0 + a == CP) && (c0 == CP)) ? 1.0f : 0.0f,
                      ((r0 + a == CP) && (c0 + 1 == CP)) ? 1.0f : 0.0f);
    }
    {
        float ahxU = (r0 > 0) ? p.ahxP[r0 - 1] : 0.0f;   // table idx guard
        float ahyL = (c0 > 0) ? p.ahyP[c0 - 1] : 0.0f;
        dHyU = mk2(ahxU * p.aeyP[c0], ahxU * p.aeyP[c0 + 1]);
        dHxL[0] = p.aexP[r0] * ahyL;
        dHxL[1] = p.aexP[r0 + 1] * ahyL;
    }

    const bool odd = (t & 1) != 0;
    const float* cEz = odd ? p.bEz : p.aEz;
    const float* cJz = odd ? p.bJz : p.aJz;
    const float* cU  = odd ? p.bU  : p.aU;
    const float* cHx = odd ? p.bHx : p.aHx;
    const float* cHy = odd ? p.bHy : p.aHy;
    float* nEz = odd ? p.aEz : p.bEz;
    float* nJz = odd ? p.aJz : p.bJz;
    float* nU  = odd ? p.aU  : p.bU;
    float* nHx = odd ? p.aHx : p.bHx;
    float* nHy = odd ? p.aHy : p.bHy;

    // Zero the whole LDS tile once (covers the permanent ring). Must be
    // barrier-separated from the step-0 interior publishes (same addresses).
    {
        float* sp = &sEz[0][0][0];
        for (int z = tid; z < 2 * LROWS * SPITCH; z += 256) sp[z] = 0.0f;
    }

    // Load 2x2 register state (unconditional padded float2) as packed rows
    v2f ez[2], jz[2], uu[2], hx[2], hy[2];
#pragma unroll
    for (int a = 0; a < 2; ++a) {
        int g = (r0 + a) * PP + c0;
        float2 v;
        v = *(const float2*)&cEz[g]; ez[a] = mk2(v.x, v.y);
        v = *(const float2*)&cJz[g]; jz[a] = mk2(v.x, v.y);
        v = *(const float2*)&cU[g];  uu[a] = mk2(v.x, v.y);
        v = *(const float2*)&cHx[g]; hx[a] = mk2(v.x, v.y);
        v = *(const float2*)&cHy[g]; hy[a] = mk2(v.x, v.y);
    }
    // Ghost H (row above / col left); guard row + zero pads make -1 safe
    v2f hyU;
    float hxL[2];
    {
        float2 v = *(const float2*)&cHy[(r0 - 1) * PP + c0];
        hyU = mk2(v.x, v.y);
        hxL[0] = cHx[r0 * PP + c0 - 1];
        hxL[1] = cHx[(r0 + 1) * PP + c0 - 1];
    }

    // Preload the phase's Kt source values (wave-uniform -> SGPR scalar loads)
    const int n0 = t * Kt;
    float svl[Kt];
#pragma unroll
    for (int s = 0; s < Kt; ++s) svl[s] = p.src[n0 + s];

    __syncthreads();   // orders the LDS zero pass before step-0 publishes

    for (int s = 0; s < Kt; ++s) {
        float (*S)[SPITCH] = sEz[s & 1];
        // publish all 4 Ez cells into the ring-padded interior
        *(float2*)&S[1 + li0][2 + lj0] = make_float2(ez[0].x, ez[0].y);
        *(float2*)&S[2 + li0][2 + lj0] = make_float2(ez[1].x, ez[1].y);

        // ---- pre-barrier (no neighbor deps) ----
        hy[0] = dHy[0] * (hy[0] + vhy * (ez[1] - ez[0]));
        v2f w0 = hx[0] + vhx * ez[0];          // hx partial: dHx*(w - vhx*sh)
        v2f w1 = hx[1] + vhx * ez[1];

        v2f phi0 = vca1 * jz[0] + vcd * ez[0] + uu[0];
        v2f phi1 = vca1 * jz[1] + vcd * ez[1] + uu[1];
        v2f base0 = vC1 * ez[0] - vC2 * phi0;
        v2f base1 = vC1 * ez[1] - vC2 * phi1;
        v2f pj0 = phi0 - jz[0];
        v2f pj1 = phi1 - jz[1];
        uu[0] = vcb * jz[0] + vce * ez[0];     // u' for the next step
        uu[1] = vcb * jz[1] + vce * ez[1];

        __syncthreads();

        // Unconditional neighbor reads; tile-edge reads hit the zero ring.
        float eR0 = S[1 + li0][4 + lj0];
        float eR1 = S[2 + li0][4 + lj0];
        float2 eDf = *(float2*)&S[3 + li0][2 + lj0];
        float2 eUf = *(float2*)&S[li0][2 + lj0];
        float eL0 = S[1 + li0][1 + lj0];
        float eL1 = S[2 + li0][1 + lj0];
        v2f eD = mk2(eDf.x, eDf.y), eU = mk2(eUf.x, eUf.y);

        // ---- H updates (packed rows; hx needs the column-shifted ez) ----
        v2f sh0 = mk2(ez[0].y, eR0);
        v2f sh1 = mk2(ez[1].y, eR1);
        hx[0] = dHx[0] * (w0 - vhx * sh0);
        hx[1] = dHx[1] * (w1 - vhx * sh1);
        hy[1] = dHy[1] * (hy[1] + vhy * (eD - ez[1]));

        // ---- ghost H update (same arithmetic as the neighbor's own) ----
        hyU = dHyU * (hyU + vhy * (ez[0] - eU));
        hxL[0] = dHxL[0] * (hxL[0] - dbhx0 * (ez[0].x - eL0));
        hxL[1] = dHxL[1] * (hxL[1] - dbhx0 * (ez[1].x - eL1));

        // ---- curls (packed) ----
        v2f cHy0 = hy[0] - hyU;
        v2f cHy1 = hy[1] - hy[0];
        v2f cHx0 = hx[0] - mk2(hxL[0], hx[0].x);
        v2f cHx1 = hx[1] - mk2(hxL[1], hx[1].x);

        // ---- E/J update (packed short chain) ----
        float sv = svl[s];
        v2f vsv = mk2(sv, sv);
        v2f en0 = dE[0] * (base0 + vbx * cHy0 - vby * cHx0) + srcw[0] * vsv;
        v2f en1 = dE[1] * (base1 + vbx * cHy1 - vby * cHx1) + srcw[1] * vsv;
        jz[0] = pj0 + vcc * en0;
        jz[1] = pj1 + vcc * en1;
        ez[0] = en0;
        ez[1] = en1;
        // Single barrier per step: next iteration stores to the OTHER LDS
        // buffer (parity), so late readers of this buffer are safe.
    }

    // store owned interior [Kt, Kt+Bt)^2 -> ti,tj in [4,12)
    if (ti >= 4 && ti < 12 && tj >= 4 && tj < 12) {
#pragma unroll
        for (int a = 0; a < 2; ++a) {
            int g = (r0 + a) * PP + c0;
            *(float2*)&nEz[g] = make_float2(ez[a].x, ez[a].y);
            *(float2*)&nJz[g] = make_float2(jz[a].x, jz[a].y);
            *(float2*)&nU[g]  = make_float2(uu[a].x, uu[a].y);
            *(float2*)&nHx[g] = make_float2(hx[a].x, hx[a].y);
            *(float2*)&nHy[g] = make_float2(hy[a].x, hy[a].y);
        }
        // Last phase: owned regions tile the padded domain exactly; emit the
        // dense 421x421 output directly (same register values copy_out read).
        if (writeOut) {
#pragma unroll
            for (int a = 0; a < 2; ++a) {
                int gi = r0 + a - PAD;
                if (gi < NXr) {
                    int gj = c0 - PAD;
                    if (gj < NXr)     out[gi * NXr + gj]     = ez[a].x;
                    if (gj + 1 < NXr) out[gi * NXr + gj + 1] = ez[a].y;
                }
            }
        }
    }
}

// ---------------------------------------------------------------------------
extern "C" void kernel_launch(void* const* d_in, const int* in_sizes, int n_in,
                              void* d_out, int out_size, void* d_ws, size_t ws_size,
                              hipStream_t stream)
{
    const float* src    = (const float*)d_in[0];
    const float* C1     = (const float*)d_in[1];
    const float* C2     = (const float*)d_in[2];
    const float* Cb_dx  = (const float*)d_in[3];
    const float* Cb_dy  = (const float*)d_in[4];
    const float* dbhx   = (const float*)d_in[5];
    const float* dbhy   = (const float*)d_in[6];
    const float* Ca     = (const float*)d_in[7];
    const float* Cb     = (const float*)d_in[8];
    const float* Cc     = (const float*)d_in[9];
    const float* Cd     = (const float*)d_in[10];
    const float* Ce     = (const float*)d_in[11];
    const float* sig_ex = (const float*)d_in[12];
    const float* sig_ey = (const float*)d_in[13];
    const float* sig_hx = (const float*)d_in[14];
    const float* sig_hy = (const float*)d_in[15];
    // d_in[16] = n_steps (always 200) — hard-coded for graph capture.

    const double EPS0 = 1e-9 / 36.0 / M_PI;
    const double MU0  = 4.0 * M_PI * 1e-7;
    const double C0   = 1.0 / sqrt(MU0 * EPS0);
    const double DXd  = 2.5e-8, DYd = 2.5e-8;
    const double DT   = 0.99 / C0 / sqrt(1.0 / (DXd * DXd) + 1.0 / (DYd * DYd));
    const float de_fac = (float)(DT / EPS0);
    const float dh_fac = (float)(DT / MU0);

    // Workspace: [guard row PP] [10 padded fields] [6 padded tables] (~8 MB)
    float* base = (float*)d_ws;
    float* fields = base + PP;
    float* w = fields + 10 * (size_t)FSZ;
    float* dexP = w; w += PP;
    float* deyP = w; w += PP;
    float* aexP = w; w += PP;
    float* aeyP = w; w += PP;
    float* ahxP = w; w += PP;
    float* ahyP = w; w += PP;

    PParams p;
    p.aEz = fields + 0 * (size_t)FSZ;  p.aJz = fields + 1 * (size_t)FSZ;
    p.aU  = fields + 2 * (size_t)FSZ;  p.aHx = fields + 3 * (size_t)FSZ;
    p.aHy = fields + 4 * (size_t)FSZ;
    p.bEz = fields + 5 * (size_t)FSZ;  p.bJz = fields + 6 * (size_t)FSZ;
    p.bU  = fields + 7 * (size_t)FSZ;  p.bHx = fields + 8 * (size_t)FSZ;
    p.bHy = fields + 9 * (size_t)FSZ;
    p.dexP = dexP; p.deyP = deyP; p.aexP = aexP; p.aeyP = aeyP;
    p.ahxP = ahxP; p.ahyP = ahyP;
    p.C1a = C1; p.C2a = C2; p.Cbdxa = Cb_dx; p.Cbdya = Cb_dy;
    p.Caa = Ca; p.Cba = Cb; p.Cca = Cc; p.Cda = Cd; p.Cea = Ce;
    p.dbhxa = dbhx; p.dbhya = dbhy;
    p.src = src;

    init_kernel<<<512, 256, 0, stream>>>(sig_ex, sig_ey, sig_hx, sig_hy,
                                         de_fac, dh_fac,
                                         base, PP + 10 * FSZ,
                                         dexP, deyP, aexP, aeyP, ahxP, ahyP);

    dim3 blk(256);
    for (int t = 0; t < NPHASE; ++t) {
        // Support bound: after n steps the field is confined to a Chebyshev
        // ball of radius n-1 around the source. End of phase t is step 8(t+1)
        // -> radius 8t+7. Tile-based gate with R = 8t+11 has >= +10 margin
        // over the owned-region criterion. Launch sets are monotone in t ->
        // the ping-pong skip stays exact. t-only formula -> identical grids
        // every call (capture-safe).
        int R  = 8 * t + 11;
        int lo = CP - R, hi = CP + R;
        int b0 = (lo - (EXT - 1)) / 16; if (b0 < 0) b0 = 0;
        int b1 = hi / 16;               if (b1 > NBLK - 1) b1 = NBLK - 1;
        dim3 g(b1 - b0 + 1, b1 - b0 + 1);
        phase_kernel<<<g, blk, 0, stream>>>(p, t, b0, (float*)d_out,
                                            (t == NPHASE - 1) ? 1 : 0);
    }
    // No copy_out dispatch: phase t=24 wrote the dense output directly.
}

// Round 8
// 245.052 us; speedup vs baseline: 1.1863x; 1.0054x over previous
//
#include <hip/hip_runtime.h>
#include <math.h>

// Real grid (match reference): 421 x 421 E-grid, source at (210,210)
#define NXr 421
#define CXr 210
#define NSTEPS_C 200

// Round 19 = R18 (packed v2f body + 5-field state, 246.4 us) with:
//  1) 1024-thread SEED: steps 0..31 in one dispatch, one block, 32x32 threads
//     x 2x2 cells = 64x64 tile, 16 waves (4/SIMD -> real latency hiding; the
//     R14 seed failed at 4 waves). Replaces phases t=0..3: dispatches 26->23.
//  2) Ring-only LDS zero + NO pre-loop barrier: publishes never touch the
//     ring, so the WAW that forced the barrier is gone; the step-0 in-loop
//     barrier orders ring-zero vs all readers.
// Everything else identical to R18 (Kt=8/Bt=16/EXT=32, swizzle, gating).
#define Bt   16
#define Kt   8
#define EXT  32
#define LROWS (EXT + 2)            // 34: zero ring row above/below
#define SPITCH 36                  // 2+32+2 cols, even => float2-aligned interior
#define RING_N (2 * SPITCH + (LROWS - 2) * 4)   // 200 ring cells per buffer
#define NBLK 27                    // 27*16 = 432 computational domain
#define NPHASE (NSTEPS_C / Kt)     // 25 step-phases; 0..3 done by seed

// Padded zero-ring layout: fields are PP x PP with the computational domain
// [0,432)^2 at offset (PAD,PAD). Coefficient tables are zero outside the real
// 421^2 domain, so cells outside it provably stay 0 forever -> all hot
// loads/stores are unconditional float2 (u = cb*0+ce*0 = 0 preserved). A
// zeroed guard row (PP floats) sits in front of the field block so ghost
// loads at padded row/col -1 are safe.
#define PP   448
#define PAD  8
#define CP   (CXr + PAD)           // source in padded coords: 218
#define FSZ  (PP * PP)             // floats per padded field

// Seed tile: 64x64 cells at rows/cols [SB, SB+64) = [CP-32, CP+32)
#define SB   (CP - 32)             // 186
#define SEED_STEPS 32              // support radius <= 31 stays inside tile
#define SROWS 66                   // 1 + 64 + 1 ring rows
#define SPITCH2 68                 // 2+64+2 cols
#define RING_N2 (2 * SPITCH2 + (SROWS - 2) * 4) // 392 ring cells per buffer

typedef float v2f __attribute__((ext_vector_type(2)));
static __device__ __forceinline__ v2f mk2(float x, float y)
{ v2f r; r.x = x; r.y = y; return r; }

struct PParams {
    float *aEz, *aJz, *aU, *aHx, *aHy;          // state set A (5 fields)
    float *bEz, *bJz, *bU, *bHx, *bHy;          // state set B
    const float *dexP, *deyP, *aexP, *aeyP, *ahxP, *ahyP;  // padded 1-D tables
    const float *C1a, *C2a, *Cbdxa, *Cbdya;
    const float *Caa, *Cba, *Cca, *Cda, *Cea, *dbhxa, *dbhya;
    const float *src;
};

// ---------------------------------------------------------------------------
// Init: zero guard row + both padded state sets; build padded coeff tables.
// dexP/deyP fold the interior mask (nonzero only for real coords 1..419).
// Zeroing BOTH sets every call keeps the support-gating skip exact.
// ---------------------------------------------------------------------------
__global__ void init_kernel(const float* __restrict__ sig_ex,
                            const float* __restrict__ sig_ey,
                            const float* __restrict__ sig_hx,
                            const float* __restrict__ sig_hy,
                            float de_fac, float dh_fac,
                            float* __restrict__ zero_base, int n_zero,
                            float* __restrict__ dexP, float* __restrict__ deyP,
                            float* __restrict__ aexP, float* __restrict__ aeyP,
                            float* __restrict__ ahxP, float* __restrict__ ahyP)
{
    int t = blockIdx.x * blockDim.x + threadIdx.x;
    int stride = gridDim.x * blockDim.x;
    for (int k = t; k < n_zero; k += stride) zero_base[k] = 0.0f;
    if (t < PP) {
        int g = t - PAD;
        dexP[t] = (g >= 1 && g <= NXr - 2) ? expf(-sig_ex[g] * de_fac) : 0.0f;
        deyP[t] = (g >= 1 && g <= NXr - 2) ? expf(-sig_ey[g] * de_fac) : 0.0f;
        aexP[t] = (g >= 0 && g <  NXr)     ? expf(-sig_ex[g] * dh_fac) : 0.0f;
        aeyP[t] = (g >= 0 && g <  NXr)     ? expf(-sig_ey[g] * dh_fac) : 0.0f;
        ahxP[t] = (g >= 0 && g <  NXr - 1) ? expf(-sig_hx[g] * dh_fac) : 0.0f;
        ahyP[t] = (g >= 0 && g <  NXr - 1) ? expf(-sig_hy[g] * dh_fac) : 0.0f;
    }
}

// ---------------------------------------------------------------------------
// Seed: steps 0..31 in one dispatch, ONE 1024-thread block (16 waves).
// 32x32 threads x 2x2 cells = 64x64 tile centered on the source. State
// starts exactly zero -> no global loads, no redundancy. Ring reads return
// 0 = true field (support radius <= 31 stays strictly inside the tile).
// Same packed v2f step body as phase_kernel. Writes step-32 state to set A.
// ---------------------------------------------------------------------------
__global__ __launch_bounds__(1024)
void seed_kernel(PParams p)
{
    __shared__ __align__(16) float sE[2][SROWS][SPITCH2];

    const int tid = threadIdx.x;
    const int tj = tid & 31, ti = tid >> 5;
    const int li0 = 2 * ti, lj0 = 2 * tj;
    const int r0 = SB + li0, c0 = SB + lj0;   // padded coords

    const float ca = p.Caa[0], cb = p.Cba[0], cc = p.Cca[0];
    const float cd = p.Cda[0], ce = p.Cea[0];
    const float ca1f = ca + 1.0f;
    const float C1f = p.C1a[0], C2f = p.C2a[0];
    const float cbdxf = p.Cbdxa[0], cbdyf = p.Cbdya[0];
    const float dbhx0 = p.dbhxa[0], dbhy0 = p.dbhya[0];

    const v2f vca1 = mk2(ca1f, ca1f), vcb = mk2(cb, cb), vcc = mk2(cc, cc);
    const v2f vcd = mk2(cd, cd), vce = mk2(ce, ce);
    const v2f vC1 = mk2(C1f, C1f), vC2 = mk2(C2f, C2f);
    const v2f vbx = mk2(cbdxf, cbdxf), vby = mk2(cbdyf, cbdyf);
    const v2f vhx = mk2(dbhx0, dbhx0), vhy = mk2(dbhy0, dbhy0);

    v2f dHx[2], dHy[2], dE[2], dHyU, srcw[2];
    float dHxL[2];
#pragma unroll
    for (int a = 0; a < 2; ++a) {
        float aex = p.aexP[r0 + a], ahxv = p.ahxP[r0 + a], dex = p.dexP[r0 + a];
        dHx[a] = mk2(aex * p.ahyP[c0], aex * p.ahyP[c0 + 1]);
        dHy[a] = mk2(ahxv * p.aeyP[c0], ahxv * p.aeyP[c0 + 1]);
        dE[a]  = mk2(dex * p.deyP[c0], dex * p.deyP[c0 + 1]);
        srcw[a] = mk2(((r0 + a == CP) && (c0 == CP)) ? 1.0f : 0.0f,
                      ((r0 + a == CP) && (c0 + 1 == CP)) ? 1.0f : 0.0f);
    }
    {
        float ahxU = p.ahxP[r0 - 1];          // r0-1 >= SB-1 = 185 >= 0
        float ahyL = p.ahyP[c0 - 1];
        dHyU = mk2(ahxU * p.aeyP[c0], ahxU * p.aeyP[c0 + 1]);
        dHxL[0] = p.aexP[r0] * ahyL;
        dHxL[1] = p.aexP[r0 + 1] * ahyL;
    }

    // Zero state (exact at t=0) -- no global loads at all.
    v2f ez[2] = {}, jz[2] = {}, uu[2] = {}, hx[2] = {}, hy[2] = {};
    v2f hyU = {};
    float hxL[2] = {};

    // Ring-only zero (publishes never touch the ring) -> no barrier needed;
    // the step-0 in-loop barrier orders these writes vs all readers.
    for (int z = tid; z < 2 * RING_N2; z += 1024) {
        int b = (z >= RING_N2) ? 1 : 0;
        int r = b ? z - RING_N2 : z;
        int row, col;
        if (r < 2 * SPITCH2) { row = (r < SPITCH2) ? 0 : (SROWS - 1); col = r % SPITCH2; }
        else { int rr = r - 2 * SPITCH2; row = 1 + (rr >> 2); int c = rr & 3;
               col = (c < 2) ? c : c + 64; }
        sE[b][row][col] = 0.0f;
    }

    // Preload all 32 source values (wave-uniform -> SGPRs)
    float svl[SEED_STEPS];
#pragma unroll
    for (int s = 0; s < SEED_STEPS; ++s) svl[s] = p.src[s];

    for (int s = 0; s < SEED_STEPS; ++s) {
        float (*S)[SPITCH2] = sE[s & 1];
        *(float2*)&S[1 + li0][2 + lj0] = make_float2(ez[0].x, ez[0].y);
        *(float2*)&S[2 + li0][2 + lj0] = make_float2(ez[1].x, ez[1].y);

        // ---- pre-barrier (no neighbor deps) ----
        hy[0] = dHy[0] * (hy[0] + vhy * (ez[1] - ez[0]));
        v2f w0 = hx[0] + vhx * ez[0];
        v2f w1 = hx[1] + vhx * ez[1];

        v2f phi0 = vca1 * jz[0] + vcd * ez[0] + uu[0];
        v2f phi1 = vca1 * jz[1] + vcd * ez[1] + uu[1];
        v2f base0 = vC1 * ez[0] - vC2 * phi0;
        v2f base1 = vC1 * ez[1] - vC2 * phi1;
        v2f pj0 = phi0 - jz[0];
        v2f pj1 = phi1 - jz[1];
        uu[0] = vcb * jz[0] + vce * ez[0];
        uu[1] = vcb * jz[1] + vce * ez[1];

        __syncthreads();

        float eR0 = S[1 + li0][4 + lj0];
        float eR1 = S[2 + li0][4 + lj0];
        float2 eDf = *(float2*)&S[3 + li0][2 + lj0];
        float2 eUf = *(float2*)&S[li0][2 + lj0];
        float eL0 = S[1 + li0][1 + lj0];
        float eL1 = S[2 + li0][1 + lj0];
        v2f eD = mk2(eDf.x, eDf.y), eU = mk2(eUf.x, eUf.y);

        v2f sh0 = mk2(ez[0].y, eR0);
        v2f sh1 = mk2(ez[1].y, eR1);
        hx[0] = dHx[0] * (w0 - vhx * sh0);
        hx[1] = dHx[1] * (w1 - vhx * sh1);
        hy[1] = dHy[1] * (hy[1] + vhy * (eD - ez[1]));

        hyU = dHyU * (hyU + vhy * (ez[0] - eU));
        hxL[0] = dHxL[0] * (hxL[0] - dbhx0 * (ez[0].x - eL0));
        hxL[1] = dHxL[1] * (hxL[1] - dbhx0 * (ez[1].x - eL1));

        v2f cHy0 = hy[0] - hyU;
        v2f cHy1 = hy[1] - hy[0];
        v2f cHx0 = hx[0] - mk2(hxL[0], hx[0].x);
        v2f cHx1 = hx[1] - mk2(hxL[1], hx[1].x);

        float sv = svl[s];
        v2f vsv = mk2(sv, sv);
        v2f en0 = dE[0] * (base0 + vbx * cHy0 - vby * cHx0) + srcw[0] * vsv;
        v2f en1 = dE[1] * (base1 + vbx * cHy1 - vby * cHx1) + srcw[1] * vsv;
        jz[0] = pj0 + vcc * en0;
        jz[1] = pj1 + vcc * en1;
        ez[0] = en0;
        ez[1] = en1;
    }

    // Write step-32 state to set A (phase t=4 is even -> reads A).
#pragma unroll
    for (int a = 0; a < 2; ++a) {
        int g = (r0 + a) * PP + c0;
        *(float2*)&p.aEz[g] = make_float2(ez[a].x, ez[a].y);
        *(float2*)&p.aJz[g] = make_float2(jz[a].x, jz[a].y);
        *(float2*)&p.aU[g]  = make_float2(uu[a].x, uu[a].y);
        *(float2*)&p.aHx[g] = make_float2(hx[a].x, hx[a].y);
        *(float2*)&p.aHy[g] = make_float2(hy[a].x, hy[a].y);
    }
}

// ---------------------------------------------------------------------------
// One temporal-blocked phase (Kt=8 steps), ONE barrier per step.
// Ez is the only field exchanged through LDS (parity-double-buffered tile:
// step s+1 stores to the other buffer, so the single barrier is WAR-safe).
// Ring-only zero (no pre-loop barrier; step-0 barrier orders it vs readers).
// Pre-barrier: publish Ez, hy[0], hx-partial w, Lorentz terms phi/base/pj/u'.
// Post-barrier: 6 LDS reads -> remaining H, ghost H, curls, packed E/J.
// writeOut: last phase writes its owned Ez directly to the dense output.
// ---------------------------------------------------------------------------
__global__ __launch_bounds__(256)
void phase_kernel(PParams p, int t, int b0, float* __restrict__ out,
                  int writeOut)
{
    __shared__ __align__(16) float sEz[2][LROWS][SPITCH];

    const int tid = threadIdx.x;
    const int tj = tid & 15, ti = tid >> 4;
    const int li0 = 2 * ti, lj0 = 2 * tj;

    // Bijective XCD-chunked swizzle (grid is always square). Pure permutation.
    const int gx = (int)gridDim.x;
    int orig = (int)blockIdx.y * gx + (int)blockIdx.x;
    int nwg = gx * gx;
    int q = nwg >> 3, rr = nwg & 7;
    int xcd = orig & 7, kk = orig >> 3;
    int nid = (xcd < rr ? xcd * (q + 1) : rr * (q + 1) + (xcd - rr) * q) + kk;
    int bx = nid % gx, by = nid / gx;

    const int r0 = (bx + b0) * Bt + li0;  // padded row, cell(0,*)
    const int c0 = (by + b0) * Bt + lj0;  // padded col, cell(*,0)

    const float ca = p.Caa[0], cb = p.Cba[0], cc = p.Cca[0];
    const float cd = p.Cda[0], ce = p.Cea[0];
    const float ca1f = ca + 1.0f;
    const float C1f = p.C1a[0], C2f = p.C2a[0];
    const float cbdxf = p.Cbdxa[0], cbdyf = p.Cbdya[0];
    const float dbhx0 = p.dbhxa[0], dbhy0 = p.dbhya[0];

    const v2f vca1 = mk2(ca1f, ca1f), vcb = mk2(cb, cb), vcc = mk2(cc, cc);
    const v2f vcd = mk2(cd, cd), vce = mk2(ce, ce);
    const v2f vC1 = mk2(C1f, C1f), vC2 = mk2(C2f, C2f);
    const v2f vbx = mk2(cbdxf, cbdxf), vby = mk2(cbdyf, cbdyf);
    const v2f vhx = mk2(dbhx0, dbhx0), vhy = mk2(dbhy0, dbhy0);

    v2f dHx[2], dHy[2], dE[2], dHyU, srcw[2];
    float dHxL[2];
#pragma unroll
    for (int a = 0; a < 2; ++a) {
        float aex = p.aexP[r0 + a], ahxv = p.ahxP[r0 + a], dex = p.dexP[r0 + a];
        dHx[a] = mk2(aex * p.ahyP[c0], aex * p.ahyP[c0 + 1]);
        dHy[a] = mk2(ahxv * p.aeyP[c0], ahxv * p.aeyP[c0 + 1]);
        dE[a]  = mk2(dex * p.deyP[c0], dex * p.deyP[c0 + 1]);
        srcw[a] = mk2(((r0 + a == CP) && (c0 == CP)) ? 1.0f : 0.0f,
                      ((r0 + a == CP) && (c0 + 1 == CP)) ? 1.0f : 0.0f);
    }
    {
        float ahxU = (r0 > 0) ? p.ahxP[r0 - 1] : 0.0f;   // table idx guard
        float ahyL = (c0 > 0) ? p.ahyP[c0 - 1] : 0.0f;
        dHyU = mk2(ahxU * p.aeyP[c0], ahxU * p.aeyP[c0 + 1]);
        dHxL[0] = p.aexP[r0] * ahyL;
        dHxL[1] = p.aexP[r0 + 1] * ahyL;
    }

    const bool odd = (t & 1) != 0;
    const float* cEz = odd ? p.bEz : p.aEz;
    const float* cJz = odd ? p.bJz : p.aJz;
    const float* cU  = odd ? p.bU  : p.aU;
    const float* cHx = odd ? p.bHx : p.aHx;
    const float* cHy = odd ? p.bHy : p.aHy;
    float* nEz = odd ? p.aEz : p.bEz;
    float* nJz = odd ? p.aJz : p.bJz;
    float* nU  = odd ? p.aU  : p.bU;
    float* nHx = odd ? p.aHx : p.bHx;
    float* nHy = odd ? p.aHy : p.bHy;

    // Ring-only zero (publishes never touch the ring) -> no barrier needed;
    // the step-0 in-loop barrier orders these writes vs all readers.
    for (int z = tid; z < 2 * RING_N; z += 256) {
        int b = (z >= RING_N) ? 1 : 0;
        int r = b ? z - RING_N : z;
        int row, col;
        if (r < 2 * SPITCH) { row = (r < SPITCH) ? 0 : (LROWS - 1); col = r % SPITCH; }
        else { int rr2 = r - 2 * SPITCH; row = 1 + (rr2 >> 2); int c = rr2 & 3;
               col = (c < 2) ? c : c + EXT; }
        sEz[b][row][col] = 0.0f;
    }

    // Load 2x2 register state (unconditional padded float2) as packed rows
    v2f ez[2], jz[2], uu[2], hx[2], hy[2];
#pragma unroll
    for (int a = 0; a < 2; ++a) {
        int g = (r0 + a) * PP + c0;
        float2 v;
        v = *(const float2*)&cEz[g]; ez[a] = mk2(v.x, v.y);
        v = *(const float2*)&cJz[g]; jz[a] = mk2(v.x, v.y);
        v = *(const float2*)&cU[g];  uu[a] = mk2(v.x, v.y);
        v = *(const float2*)&cHx[g]; hx[a] = mk2(v.x, v.y);
        v = *(const float2*)&cHy[g]; hy[a] = mk2(v.x, v.y);
    }
    // Ghost H (row above / col left); guard row + zero pads make -1 safe
    v2f hyU;
    float hxL[2];
    {
        float2 v = *(const float2*)&cHy[(r0 - 1) * PP + c0];
        hyU = mk2(v.x, v.y);
        hxL[0] = cHx[r0 * PP + c0 - 1];
        hxL[1] = cHx[(r0 + 1) * PP + c0 - 1];
    }

    // Preload the phase's Kt source values (wave-uniform -> SGPR scalar loads)
    const int n0 = t * Kt;
    float svl[Kt];
#pragma unroll
    for (int s = 0; s < Kt; ++s) svl[s] = p.src[n0 + s];

    for (int s = 0; s < Kt; ++s) {
        float (*S)[SPITCH] = sEz[s & 1];
        // publish all 4 Ez cells into the ring-padded interior
        *(float2*)&S[1 + li0][2 + lj0] = make_float2(ez[0].x, ez[0].y);
        *(float2*)&S[2 + li0][2 + lj0] = make_float2(ez[1].x, ez[1].y);

        // ---- pre-barrier (no neighbor deps) ----
        hy[0] = dHy[0] * (hy[0] + vhy * (ez[1] - ez[0]));
        v2f w0 = hx[0] + vhx * ez[0];          // hx partial: dHx*(w - vhx*sh)
        v2f w1 = hx[1] + vhx * ez[1];

        v2f phi0 = vca1 * jz[0] + vcd * ez[0] + uu[0];
        v2f phi1 = vca1 * jz[1] + vcd * ez[1] + uu[1];
        v2f base0 = vC1 * ez[0] - vC2 * phi0;
        v2f base1 = vC1 * ez[1] - vC2 * phi1;
        v2f pj0 = phi0 - jz[0];
        v2f pj1 = phi1 - jz[1];
        uu[0] = vcb * jz[0] + vce * ez[0];     // u' for the next step
        uu[1] = vcb * jz[1] + vce * ez[1];

        __syncthreads();

        // Unconditional neighbor reads; tile-edge reads hit the zero ring.
        float eR0 = S[1 + li0][4 + lj0];
        float eR1 = S[2 + li0][4 + lj0];
        float2 eDf = *(float2*)&S[3 + li0][2 + lj0];
        float2 eUf = *(float2*)&S[li0][2 + lj0];
        float eL0 = S[1 + li0][1 + lj0];
        float eL1 = S[2 + li0][1 + lj0];
        v2f eD = mk2(eDf.x, eDf.y), eU = mk2(eUf.x, eUf.y);

        // ---- H updates (packed rows; hx needs the column-shifted ez) ----
        v2f sh0 = mk2(ez[0].y, eR0);
        v2f sh1 = mk2(ez[1].y, eR1);
        hx[0] = dHx[0] * (w0 - vhx * sh0);
        hx[1] = dHx[1] * (w1 - vhx * sh1);
        hy[1] = dHy[1] * (hy[1] + vhy * (eD - ez[1]));

        // ---- ghost H update (same arithmetic as the neighbor's own) ----
        hyU = dHyU * (hyU + vhy * (ez[0] - eU));
        hxL[0] = dHxL[0] * (hxL[0] - dbhx0 * (ez[0].x - eL0));
        hxL[1] = dHxL[1] * (hxL[1] - dbhx0 * (ez[1].x - eL1));

        // ---- curls (packed) ----
        v2f cHy0 = hy[0] - hyU;
        v2f cHy1 = hy[1] - hy[0];
        v2f cHx0 = hx[0] - mk2(hxL[0], hx[0].x);
        v2f cHx1 = hx[1] - mk2(hxL[1], hx[1].x);

        // ---- E/J update (packed short chain) ----
        float sv = svl[s];
        v2f vsv = mk2(sv, sv);
        v2f en0 = dE[0] * (base0 + vbx * cHy0 - vby * cHx0) + srcw[0] * vsv;
        v2f en1 = dE[1] * (base1 + vbx * cHy1 - vby * cHx1) + srcw[1] * vsv;
        jz[0] = pj0 + vcc * en0;
        jz[1] = pj1 + vcc * en1;
        ez[0] = en0;
        ez[1] = en1;
        // Single barrier per step: next iteration stores to the OTHER LDS
        // buffer (parity), so late readers of this buffer are safe.
    }

    // store owned interior [Kt, Kt+Bt)^2 -> ti,tj in [4,12)
    if (ti >= 4 && ti < 12 && tj >= 4 && tj < 12) {
#pragma unroll
        for (int a = 0; a < 2; ++a) {
            int g = (r0 + a) * PP + c0;
            *(float2*)&nEz[g] = make_float2(ez[a].x, ez[a].y);
            *(float2*)&nJz[g] = make_float2(jz[a].x, jz[a].y);
            *(float2*)&nU[g]  = make_float2(uu[a].x, uu[a].y);
            *(float2*)&nHx[g] = make_float2(hx[a].x, hx[a].y);
            *(float2*)&nHy[g] = make_float2(hy[a].x, hy[a].y);
        }
        // Last phase: owned regions tile the padded domain exactly; emit the
        // dense 421x421 output directly (same register values copy_out read).
        if (writeOut) {
#pragma unroll
            for (int a = 0; a < 2; ++a) {
                int gi = r0 + a - PAD;
                if (gi < NXr) {
                    int gj = c0 - PAD;
                    if (gj < NXr)     out[gi * NXr + gj]     = ez[a].x;
                    if (gj + 1 < NXr) out[gi * NXr + gj + 1] = ez[a].y;
                }
            }
        }
    }
}

// ---------------------------------------------------------------------------
extern "C" void kernel_launch(void* const* d_in, const int* in_sizes, int n_in,
                              void* d_out, int out_size, void* d_ws, size_t ws_size,
                              hipStream_t stream)
{
    const float* src    = (const float*)d_in[0];
    const float* C1     = (const float*)d_in[1];
    const float* C2     = (const float*)d_in[2];
    const float* Cb_dx  = (const float*)d_in[3];
    const float* Cb_dy  = (const float*)d_in[4];
    const float* dbhx   = (const float*)d_in[5];
    const float* dbhy   = (const float*)d_in[6];
    const float* Ca     = (const float*)d_in[7];
    const float* Cb     = (const float*)d_in[8];
    const float* Cc     = (const float*)d_in[9];
    const float* Cd     = (const float*)d_in[10];
    const float* Ce     = (const float*)d_in[11];
    const float* sig_ex = (const float*)d_in[12];
    const float* sig_ey = (const float*)d_in[13];
    const float* sig_hx = (const float*)d_in[14];
    const float* sig_hy = (const float*)d_in[15];
    // d_in[16] = n_steps (always 200) — hard-coded for graph capture.

    const double EPS0 = 1e-9 / 36.0 / M_PI;
    const double MU0  = 4.0 * M_PI * 1e-7;
    const double C0   = 1.0 / sqrt(MU0 * EPS0);
    const double DXd  = 2.5e-8, DYd = 2.5e-8;
    const double DT   = 0.99 / C0 / sqrt(1.0 / (DXd * DXd) + 1.0 / (DYd * DYd));
    const float de_fac = (float)(DT / EPS0);
    const float dh_fac = (float)(DT / MU0);

    // Workspace: [guard row PP] [10 padded fields] [6 padded tables] (~8 MB)
    float* base = (float*)d_ws;
    float* fields = base + PP;
    float* w = fields + 10 * (size_t)FSZ;
    float* dexP = w; w += PP;
    float* deyP = w; w += PP;
    float* aexP = w; w += PP;
    float* aeyP = w; w += PP;
    float* ahxP = w; w += PP;
    float* ahyP = w; w += PP;

    PParams p;
    p.aEz = fields + 0 * (size_t)FSZ;  p.aJz = fields + 1 * (size_t)FSZ;
    p.aU  = fields + 2 * (size_t)FSZ;  p.aHx = fields + 3 * (size_t)FSZ;
    p.aHy = fields + 4 * (size_t)FSZ;
    p.bEz = fields + 5 * (size_t)FSZ;  p.bJz = fields + 6 * (size_t)FSZ;
    p.bU  = fields + 7 * (size_t)FSZ;  p.bHx = fields + 8 * (size_t)FSZ;
    p.bHy = fields + 9 * (size_t)FSZ;
    p.dexP = dexP; p.deyP = deyP; p.aexP = aexP; p.aeyP = aeyP;
    p.ahxP = ahxP; p.ahyP = ahyP;
    p.C1a = C1; p.C2a = C2; p.Cbdxa = Cb_dx; p.Cbdya = Cb_dy;
    p.Caa = Ca; p.Cba = Cb; p.Cca = Cc; p.Cda = Cd; p.Cea = Ce;
    p.dbhxa = dbhx; p.dbhya = dbhy;
    p.src = src;

    init_kernel<<<512, 256, 0, stream>>>(sig_ex, sig_ey, sig_hx, sig_hy,
                                         de_fac, dh_fac,
                                         base, PP + 10 * FSZ,
                                         dexP, deyP, aexP, aeyP, ahxP, ahyP);

    // Steps 0..31 in one zero-redundancy 1024-thread dispatch. Writes set A.
    seed_kernel<<<1, 1024, 0, stream>>>(p);

    dim3 blk(256);
    for (int t = 4; t < NPHASE; ++t) {
        // Support bound: after n steps the field is confined to a Chebyshev
        // ball of radius n-1 around the source. End of phase t is step 8(t+1)
        // -> radius 8t+7. Tile-based gate with R = 8t+11 has >= +10 margin
        // over the owned-region criterion. Launch sets are monotone in t ->
        // the ping-pong skip stays exact. t-only formula -> identical grids
        // every call (capture-safe).
        int R  = 8 * t + 11;
        int lo = CP - R, hi = CP + R;
        int b0 = (lo - (EXT - 1)) / 16; if (b0 < 0) b0 = 0;
        int b1 = hi / 16;               if (b1 > NBLK - 1) b1 = NBLK - 1;
        dim3 g(b1 - b0 + 1, b1 - b0 + 1);
        phase_kernel<<<g, blk, 0, stream>>>(p, t, b0, (float*)d_out,
                                            (t == NPHASE - 1) ? 1 : 0);
    }
    // No copy_out dispatch: phase t=24 wrote the dense output directly.
}